// Round 9
// baseline (6696.577 us; speedup 1.0000x reference)
//
#include <hip/hip_runtime.h>

// VanillaRNNLayer: B=32, T=2048, I=512, H=512 — ALL FP32.
//   phase 1: xp = x @ Wx^T + bx + bh   -> fp32 into d_out (consumed in place)
//   phase 2: h_t = tanh(xp_t + Wh h_{t-1}), 8 blocks/chain, Wh slice in regs.
// R8 lesson: sc1 publish does NOT update remote L2 lines -> sc0 "fast polls"
// read stale L2 forever; there is no L2 shortcut for cross-XCD exchange.
// R9: R7-proven IC exchange (relaxed agent atomics), plus:
//   - in-register shfl_xor butterfly finish (no pacc LDS, no B-mid barrier,
//     publish spread across all 8 waves)
//   - depth-3 pipelined poll (check cadence ~lat/3 instead of ~lat)
//   - hs double-buffer -> exactly 1 barrier/step.

constexpr int Bb = 32, Tt = 2048, Ii = 512, Hh = 512;
constexpr int NP = 8;            // parts (blocks) per chain
constexpr int RP = Hh / NP;      // 64 rows per part

static __device__ __forceinline__ float fast_tanh(float x) {
    float ax = fabsf(x);
    float e = __expf(-2.0f * ax);            // in (0,1], no overflow
    float r = (1.0f - e) / (1.0f + e);
    return copysignf(r, x);
}

// ---------------- Phase 1: xp GEMM, 128x128 tile, 8x8/thread ----------------
// Measured ~0.34 ms ~= fp32 vector roofline for 34.4 GFLOP — done.
__global__ __launch_bounds__(256, 2)
void xproj_gemm(const float* __restrict__ x, const float* __restrict__ Wx,
                const float* __restrict__ bx, const float* __restrict__ bh,
                float* __restrict__ xp)
{
    constexpr int BM = 128, BK = 16, LDT = BM + 4;   // [k][m] transposed tiles
    __shared__ float As[BK][LDT];
    __shared__ float Bs[BK][LDT];

    const int tid = threadIdx.x;
    const int m0 = blockIdx.x * BM;
    const int n0 = blockIdx.y * BM;
    const int lrow = tid >> 1;               // 0..127
    const int lkh  = (tid & 1) * 8;          // 0 or 8
    const int tx = tid & 15, ty = tid >> 4;

    float acc[2][2][4][4] = {};

    for (int k0 = 0; k0 < Ii; k0 += BK) {
        float4 a0 = *reinterpret_cast<const float4*>(&x[(size_t)(m0 + lrow) * Ii + k0 + lkh]);
        float4 a1 = *reinterpret_cast<const float4*>(&x[(size_t)(m0 + lrow) * Ii + k0 + lkh + 4]);
        float4 b0 = *reinterpret_cast<const float4*>(&Wx[(size_t)(n0 + lrow) * Ii + k0 + lkh]);
        float4 b1 = *reinterpret_cast<const float4*>(&Wx[(size_t)(n0 + lrow) * Ii + k0 + lkh + 4]);
        __syncthreads();
        As[lkh + 0][lrow] = a0.x; As[lkh + 1][lrow] = a0.y;
        As[lkh + 2][lrow] = a0.z; As[lkh + 3][lrow] = a0.w;
        As[lkh + 4][lrow] = a1.x; As[lkh + 5][lrow] = a1.y;
        As[lkh + 6][lrow] = a1.z; As[lkh + 7][lrow] = a1.w;
        Bs[lkh + 0][lrow] = b0.x; Bs[lkh + 1][lrow] = b0.y;
        Bs[lkh + 2][lrow] = b0.z; Bs[lkh + 3][lrow] = b0.w;
        Bs[lkh + 4][lrow] = b1.x; Bs[lkh + 5][lrow] = b1.y;
        Bs[lkh + 6][lrow] = b1.z; Bs[lkh + 7][lrow] = b1.w;
        __syncthreads();
        #pragma unroll
        for (int k = 0; k < BK; ++k) {
            float4 av[2], bv[2];
            av[0] = *reinterpret_cast<const float4*>(&As[k][ty * 4]);
            av[1] = *reinterpret_cast<const float4*>(&As[k][64 + ty * 4]);
            bv[0] = *reinterpret_cast<const float4*>(&Bs[k][tx * 4]);
            bv[1] = *reinterpret_cast<const float4*>(&Bs[k][64 + tx * 4]);
            #pragma unroll
            for (int rh = 0; rh < 2; ++rh) {
                const float* ap = reinterpret_cast<const float*>(&av[rh]);
                #pragma unroll
                for (int ch = 0; ch < 2; ++ch) {
                    const float* bp = reinterpret_cast<const float*>(&bv[ch]);
                    #pragma unroll
                    for (int i = 0; i < 4; ++i)
                        #pragma unroll
                        for (int j = 0; j < 4; ++j)
                            acc[rh][ch][i][j] += ap[i] * bp[j];
                }
            }
        }
    }

    float4 bias[2];
    #pragma unroll
    for (int ch = 0; ch < 2; ++ch) {
        int cb = n0 + ch * 64 + tx * 4;
        bias[ch] = make_float4(bx[cb] + bh[cb], bx[cb + 1] + bh[cb + 1],
                               bx[cb + 2] + bh[cb + 2], bx[cb + 3] + bh[cb + 3]);
    }
    #pragma unroll
    for (int rh = 0; rh < 2; ++rh)
        #pragma unroll
        for (int i = 0; i < 4; ++i) {
            size_t row = (size_t)(m0 + rh * 64 + ty * 4 + i);
            #pragma unroll
            for (int ch = 0; ch < 2; ++ch) {
                const float* bp = reinterpret_cast<const float*>(&bias[ch]);
                float4 v = make_float4(acc[rh][ch][i][0] + bp[0], acc[rh][ch][i][1] + bp[1],
                                       acc[rh][ch][i][2] + bp[2], acc[rh][ch][i][3] + bp[3]);
                *reinterpret_cast<float4*>(&xp[row * Hh + n0 + ch * 64 + tx * 4]) = v;
            }
        }
}

// ---------------- zero xbuf (every launch: tags per-launch monotonic) -------
__global__ void zero_xbuf(unsigned long long* __restrict__ xb)
{
    xb[(size_t)blockIdx.x * 512 + threadIdx.x] = 0ull;   // 64 blocks x 512
}

// ---------------- Phase 2: scan, 8 blocks/chain, butterfly finish -----------
// bid: chain c = bid&31, part P = bid>>5. Wave w (0..7), lane=(hf,lp):
// thread rows P*64 + w*8 + hf*4 + s (s=0..3), cols q*128 + lp*4 + i.
// After FMA: 5-stage shfl_xor butterfly over lp -> every lane holds its 4
// complete row sums. Lanes lp<4 (8 per wave) finish+publish their row.
// Waves w!=P poll part w's {tag,val} qwords with a depth-3 pipelined poll.
__global__ __launch_bounds__(512, 1)
void rnn_scan_mb(const float* __restrict__ Wh, const float* __restrict__ h0,
                 float* __restrict__ out, unsigned long long* __restrict__ xbuf)
{
    const int bid = blockIdx.x;
    const int c = bid & 31;
    const int P = bid >> 5;
    const int tid = threadIdx.x;
    const int w = tid >> 6;          // wave 0..7
    const int lane = tid & 63;
    const int hf = lane >> 5, lp = lane & 31;
    const int lrow0 = w * 8 + hf * 4;          // local row base 0..60

    __shared__ __align__(16) float hsd[2][Hh];   // double-buffered h

    // ---- weights -> registers via opaque asm loads (no remat possible) ----
    float4 wreg[4][4];
    #pragma unroll
    for (int s = 0; s < 4; ++s)
        #pragma unroll
        for (int q = 0; q < 4; ++q) {
            const float* ap = &Wh[(size_t)(P * RP + lrow0 + s) * Hh + q * 128 + lp * 4];
            asm volatile("global_load_dwordx4 %0, %1, off"
                         : "=v"(wreg[s][q]) : "v"(ap));
        }
    asm volatile("s_waitcnt vmcnt(0)" ::: "memory");

    hsd[0][tid] = h0[(size_t)c * Hh + tid];

    float* ob = out + (size_t)c * Tt * Hh;                // xp -> h in place
    unsigned long long* xb = xbuf + (size_t)c * 2 * Hh;   // [slot][row]

    const bool isPub = (lp < 4);
    const int grow = P * RP + lrow0 + lp;     // this lane's output row (isPub only)

    float xp_cur = 0.f;
    if (isPub) xp_cur = ob[grow];             // xp row t=0
    __syncthreads();                          // hsd[0] ready

    for (int t = 0; t < Tt; ++t) {
        const int cur = t & 1, nxt = cur ^ 1;

        // prefetch next xp early (latency hides under FMA+butterfly)
        float xp_nxt = 0.f;
        if (isPub && t + 1 < Tt) xp_nxt = ob[(size_t)(t + 1) * Hh + grow];

        // ---- FMA: 4 rows x 16 interleaved cols per thread
        const float* h = hsd[cur];
        float4 hv[4];
        #pragma unroll
        for (int q = 0; q < 4; ++q)
            hv[q] = *reinterpret_cast<const float4*>(&h[q * 128 + lp * 4]);
        float acc0 = 0.f, acc1 = 0.f, acc2 = 0.f, acc3 = 0.f;
        #pragma unroll
        for (int q = 0; q < 4; ++q) {
            const float* hq = reinterpret_cast<const float*>(&hv[q]);
            const float* w0 = reinterpret_cast<const float*>(&wreg[0][q]);
            const float* w1 = reinterpret_cast<const float*>(&wreg[1][q]);
            const float* w2 = reinterpret_cast<const float*>(&wreg[2][q]);
            const float* w3 = reinterpret_cast<const float*>(&wreg[3][q]);
            #pragma unroll
            for (int i = 0; i < 4; ++i) {
                acc0 += w0[i] * hq[i];
                acc1 += w1[i] * hq[i];
                acc2 += w2[i] * hq[i];
                acc3 += w3[i] * hq[i];
            }
        }

        // ---- butterfly reduce over the 32 lp-lanes (masks < 32 stay in half)
        #pragma unroll
        for (int m = 1; m <= 16; m <<= 1) {
            acc0 += __shfl_xor(acc0, m, 64);
            acc1 += __shfl_xor(acc1, m, 64);
            acc2 += __shfl_xor(acc2, m, 64);
            acc3 += __shfl_xor(acc3, m, 64);
        }

        if (isPub) {
            // lane lp publishes row lrow0+lp  (static select, no scratch)
            float myacc = (lp == 0) ? acc0 : (lp == 1) ? acc1
                        : (lp == 2) ? acc2 : acc3;
            float hval = fast_tanh(xp_cur + myacc);
            if (t + 1 < Tt) {
                unsigned long long msg =
                    ((unsigned long long)(unsigned)(t + 1) << 32) |
                    (unsigned long long)__float_as_uint(hval);
                __hip_atomic_store(&xb[(size_t)cur * Hh + grow], msg,
                                   __ATOMIC_RELAXED, __HIP_MEMORY_SCOPE_AGENT);
                ob[(size_t)t * Hh + grow] = hval;
                hsd[nxt][grow] = hval;
                xp_cur = xp_nxt;
            } else {
                ob[(size_t)t * Hh + grow] = hval;
                out[(size_t)Bb * Tt * Hh + (size_t)c * Hh + grow] = hval;
            }
        }

        if (w != P && t + 1 < Tt) {
            // ---- depth-3 pipelined poll of part w's qword (data IS the flag)
            const unsigned want = (unsigned)(t + 1);
            const unsigned long long* pa = &xb[(size_t)cur * Hh + w * RP + lane];
            uint2 mA, mB, mC;
            asm volatile("global_load_dwordx2 %0, %1, off sc0 sc1"
                         : "=v"(mA) : "v"(pa));
            asm volatile("global_load_dwordx2 %0, %1, off sc0 sc1"
                         : "=v"(mB) : "v"(pa));
            asm volatile("global_load_dwordx2 %0, %1, off sc0 sc1"
                         : "=v"(mC) : "v"(pa));
            unsigned val;
            for (;;) {
                if (mA.y == want) { val = mA.x; break; }
                asm volatile("global_load_dwordx2 %0, %1, off sc0 sc1"
                             : "=v"(mA) : "v"(pa));
                if (mB.y == want) { val = mB.x; break; }
                asm volatile("global_load_dwordx2 %0, %1, off sc0 sc1"
                             : "=v"(mB) : "v"(pa));
                if (mC.y == want) { val = mC.x; break; }
                asm volatile("global_load_dwordx2 %0, %1, off sc0 sc1"
                             : "=v"(mC) : "v"(pa));
            }
            hsd[nxt][w * RP + lane] = __uint_as_float(val);
        }
        __syncthreads();                 // hsd[nxt] = h(t) complete
    }
}

// ---------------- Fallback single-block scan (tiny ws) ----------------
__global__ __launch_bounds__(512)
void rnn_scan_sb(const float* __restrict__ W, const float* __restrict__ h0,
                 float* __restrict__ out)
{
    const int b = blockIdx.x;
    const int j = threadIdx.x;
    __shared__ float hsb[2][Hh];
    hsb[0][j] = h0[(size_t)b * Hh + j];
    __syncthreads();

    float* ob = out + (size_t)b * Tt * Hh;
    const float* wbase = W + (size_t)j * Hh;

    float xp_cur = ob[j];
    int cur = 0;
    for (int t = 0; t < Tt; ++t) {
        float xp_next = (t + 1 < Tt) ? ob[(size_t)(t + 1) * Hh + j] : 0.0f;
        float4 a = make_float4(xp_cur, 0.0f, 0.0f, 0.0f);
        const float* h = hsb[cur];
        #pragma unroll 8
        for (int c4 = 0; c4 < Hh / 4; ++c4) {
            float4 wv = *reinterpret_cast<const float4*>(&wbase[c4 * 4]);
            float4 hv = *reinterpret_cast<const float4*>(&h[c4 * 4]);
            a.x += wv.x * hv.x; a.y += wv.y * hv.y;
            a.z += wv.z * hv.z; a.w += wv.w * hv.w;
        }
        float hn = tanhf((a.x + a.y) + (a.z + a.w));
        hsb[cur ^ 1][j] = hn;
        ob[(size_t)t * Hh + j] = hn;
        xp_cur = xp_next;
        cur ^= 1;
        __syncthreads();
    }
    out[(size_t)Bb * Tt * Hh + (size_t)b * Hh + j] = hsb[cur][j];
}

extern "C" void kernel_launch(void* const* d_in, const int* in_sizes, int n_in,
                              void* d_out, int out_size, void* d_ws, size_t ws_size,
                              hipStream_t stream)
{
    const float* x  = (const float*)d_in[0];
    const float* h0 = (const float*)d_in[1];
    const float* Wx = (const float*)d_in[2];
    const float* bx = (const float*)d_in[3];
    const float* Wh = (const float*)d_in[4];
    const float* bh = (const float*)d_in[5];
    float* out = (float*)d_out;

    dim3 g1(Bb * Tt / 128, Hh / 128);     // (512, 4)
    xproj_gemm<<<g1, 256, 0, stream>>>(x, Wx, bx, bh, out);

    const size_t xb_bytes = (size_t)Bb * 2 * Hh * sizeof(unsigned long long); // 256 KB
    if (ws_size >= xb_bytes) {
        unsigned long long* xbuf = (unsigned long long*)d_ws;
        zero_xbuf<<<64, 512, 0, stream>>>(xbuf);
        void* args[] = {(void*)&Wh, (void*)&h0, (void*)&out, (void*)&xbuf};
        hipLaunchCooperativeKernel((void*)rnn_scan_mb, dim3(NP * Bb), dim3(512),
                                   args, 0, stream);
    } else {
        rnn_scan_sb<<<Bb, Hh, 0, stream>>>(Wh, h0, out);
    }
}

// Round 10
// 3297.581 us; speedup vs baseline: 2.0308x; 2.0308x over previous
//
#include <hip/hip_runtime.h>

// VanillaRNNLayer: B=32, T=2048, I=512, H=512 — ALL FP32.
//   phase 1: xp = x @ Wx^T + bx + bh   -> fp32 into d_out (consumed in place)
//   phase 2: h_t = tanh(xp_t + Wh h_{t-1}), 8 blocks/chain, Wh slice in regs.
// R9 lessons: raw "sc0 sc1" poll loads are SYSTEM-scope -> HBM (+98MB fetch,
// 2.4x slower); shfl butterfly = 160 DS-ops/step across waves. R10: keep
// R7's PROVEN exchange encoding (__hip_atomic relaxed agent), restructure
// ownership: wave w owns [all 64 local rows] x [cols w*64..w*64+63], so the
// slice it polls is exactly what it consumes — no shared-h staging, 1
// barrier/step, finisher wave's own h never leaves registers.

constexpr int Bb = 32, Tt = 2048, Ii = 512, Hh = 512;
constexpr int NP = 8;            // parts (blocks) per chain
constexpr int RP = Hh / NP;      // 64 rows per part

static __device__ __forceinline__ float fast_tanh(float x) {
    float ax = fabsf(x);
    float e = __expf(-2.0f * ax);            // in (0,1], no overflow
    float r = (1.0f - e) / (1.0f + e);
    return copysignf(r, x);
}

// ---------------- Phase 1: xp GEMM, 128x128 tile, 8x8/thread ----------------
// Measured ~0.34 ms ~= fp32 vector roofline for 34.4 GFLOP — done.
__global__ __launch_bounds__(256, 2)
void xproj_gemm(const float* __restrict__ x, const float* __restrict__ Wx,
                const float* __restrict__ bx, const float* __restrict__ bh,
                float* __restrict__ xp)
{
    constexpr int BM = 128, BK = 16, LDT = BM + 4;   // [k][m] transposed tiles
    __shared__ float As[BK][LDT];
    __shared__ float Bs[BK][LDT];

    const int tid = threadIdx.x;
    const int m0 = blockIdx.x * BM;
    const int n0 = blockIdx.y * BM;
    const int lrow = tid >> 1;               // 0..127
    const int lkh  = (tid & 1) * 8;          // 0 or 8
    const int tx = tid & 15, ty = tid >> 4;

    float acc[2][2][4][4] = {};

    for (int k0 = 0; k0 < Ii; k0 += BK) {
        float4 a0 = *reinterpret_cast<const float4*>(&x[(size_t)(m0 + lrow) * Ii + k0 + lkh]);
        float4 a1 = *reinterpret_cast<const float4*>(&x[(size_t)(m0 + lrow) * Ii + k0 + lkh + 4]);
        float4 b0 = *reinterpret_cast<const float4*>(&Wx[(size_t)(n0 + lrow) * Ii + k0 + lkh]);
        float4 b1 = *reinterpret_cast<const float4*>(&Wx[(size_t)(n0 + lrow) * Ii + k0 + lkh + 4]);
        __syncthreads();
        As[lkh + 0][lrow] = a0.x; As[lkh + 1][lrow] = a0.y;
        As[lkh + 2][lrow] = a0.z; As[lkh + 3][lrow] = a0.w;
        As[lkh + 4][lrow] = a1.x; As[lkh + 5][lrow] = a1.y;
        As[lkh + 6][lrow] = a1.z; As[lkh + 7][lrow] = a1.w;
        Bs[lkh + 0][lrow] = b0.x; Bs[lkh + 1][lrow] = b0.y;
        Bs[lkh + 2][lrow] = b0.z; Bs[lkh + 3][lrow] = b0.w;
        Bs[lkh + 4][lrow] = b1.x; Bs[lkh + 5][lrow] = b1.y;
        Bs[lkh + 6][lrow] = b1.z; Bs[lkh + 7][lrow] = b1.w;
        __syncthreads();
        #pragma unroll
        for (int k = 0; k < BK; ++k) {
            float4 av[2], bv[2];
            av[0] = *reinterpret_cast<const float4*>(&As[k][ty * 4]);
            av[1] = *reinterpret_cast<const float4*>(&As[k][64 + ty * 4]);
            bv[0] = *reinterpret_cast<const float4*>(&Bs[k][tx * 4]);
            bv[1] = *reinterpret_cast<const float4*>(&Bs[k][64 + tx * 4]);
            #pragma unroll
            for (int rh = 0; rh < 2; ++rh) {
                const float* ap = reinterpret_cast<const float*>(&av[rh]);
                #pragma unroll
                for (int ch = 0; ch < 2; ++ch) {
                    const float* bp = reinterpret_cast<const float*>(&bv[ch]);
                    #pragma unroll
                    for (int i = 0; i < 4; ++i)
                        #pragma unroll
                        for (int j = 0; j < 4; ++j)
                            acc[rh][ch][i][j] += ap[i] * bp[j];
                }
            }
        }
    }

    float4 bias[2];
    #pragma unroll
    for (int ch = 0; ch < 2; ++ch) {
        int cb = n0 + ch * 64 + tx * 4;
        bias[ch] = make_float4(bx[cb] + bh[cb], bx[cb + 1] + bh[cb + 1],
                               bx[cb + 2] + bh[cb + 2], bx[cb + 3] + bh[cb + 3]);
    }
    #pragma unroll
    for (int rh = 0; rh < 2; ++rh)
        #pragma unroll
        for (int i = 0; i < 4; ++i) {
            size_t row = (size_t)(m0 + rh * 64 + ty * 4 + i);
            #pragma unroll
            for (int ch = 0; ch < 2; ++ch) {
                const float* bp = reinterpret_cast<const float*>(&bias[ch]);
                float4 v = make_float4(acc[rh][ch][i][0] + bp[0], acc[rh][ch][i][1] + bp[1],
                                       acc[rh][ch][i][2] + bp[2], acc[rh][ch][i][3] + bp[3]);
                *reinterpret_cast<float4*>(&xp[row * Hh + n0 + ch * 64 + tx * 4]) = v;
            }
        }
}

// ---------------- zero xbuf (every launch: tags per-launch monotonic) -------
__global__ void zero_xbuf(unsigned long long* __restrict__ xb)
{
    xb[(size_t)blockIdx.x * 512 + threadIdx.x] = 0ull;   // 64 blocks x 512
}

// ---------------- Phase 2: scan, 8 blocks/chain, col-sliced waves -----------
// bid: chain c = bid&31, part P = bid>>5.
// Wave w owns ALL 64 local rows x cols [w*64, w*64+64). Lane = local row.
// wreg[k] = Wh[P*64+lane][w*64+4k .. +3]  (16 float4 = 64 VGPR).
// Per step: wave w's h-slice (h[w*64+lane], one value/lane) -> private LDS
// bounce -> broadcast b128 reads -> 64 FMAs -> pacc[t&1][w][lane].
// One barrier. Wave P (lane=row) reduces 8 partials, tanh, publishes via
// R7-proven relaxed-agent qword {tag,val}; its own h stays in registers.
__global__ __launch_bounds__(512, 1)
void rnn_scan_mb(const float* __restrict__ Wh, const float* __restrict__ h0,
                 float* __restrict__ out, unsigned long long* __restrict__ xbuf)
{
    const int bid = blockIdx.x;
    const int c = bid & 31;
    const int P = bid >> 5;
    const int tid = threadIdx.x;
    const int w = tid >> 6;          // wave 0..7 = column-slice owner
    const int lane = tid & 63;       // local row

    __shared__ float hscratch[NP][68];     // per-wave private h-slice bounce
    __shared__ float pacc[2][NP][68];      // double-buffered partials

    // ---- weights -> registers via opaque asm loads (no remat possible) ----
    float4 wreg[16];
    #pragma unroll
    for (int k = 0; k < 16; ++k) {
        const float* ap = &Wh[(size_t)(P * RP + lane) * Hh + w * 64 + 4 * k];
        asm volatile("global_load_dwordx4 %0, %1, off"
                     : "=v"(wreg[k]) : "v"(ap));
    }
    asm volatile("s_waitcnt vmcnt(0)" ::: "memory");

    float* ob = out + (size_t)c * Tt * Hh;                // xp -> h in place
    unsigned long long* xb = xbuf + (size_t)c * 2 * Hh;   // [slot][row]

    // h_{-1} slice for this wave (one value per lane)
    float hcur = h0[(size_t)c * Hh + w * 64 + lane];
    // finisher's xp for t=0
    float xp_cur = (w == P) ? ob[P * RP + lane] : 0.f;

    for (int t = 0; t < Tt; ++t) {
        const int d = t & 1;

        // ---- stage h slice (write visible to whole wave after lgkmcnt(0))
        hscratch[w][lane] = hcur;
        asm volatile("s_waitcnt lgkmcnt(0)" ::: "memory");

        // ---- FMA: row=lane, 64 cols; 4 independent chains
        float a0 = 0.f, a1 = 0.f, a2 = 0.f, a3 = 0.f;
        #pragma unroll
        for (int k = 0; k < 16; k += 4) {
            float4 h0v = *reinterpret_cast<const float4*>(&hscratch[w][4 * k]);
            float4 h1v = *reinterpret_cast<const float4*>(&hscratch[w][4 * k + 4]);
            float4 h2v = *reinterpret_cast<const float4*>(&hscratch[w][4 * k + 8]);
            float4 h3v = *reinterpret_cast<const float4*>(&hscratch[w][4 * k + 12]);
            const float* w0 = reinterpret_cast<const float*>(&wreg[k]);
            const float* w1 = reinterpret_cast<const float*>(&wreg[k + 1]);
            const float* w2 = reinterpret_cast<const float*>(&wreg[k + 2]);
            const float* w3 = reinterpret_cast<const float*>(&wreg[k + 3]);
            a0 += w0[0] * h0v.x; a0 += w0[1] * h0v.y; a0 += w0[2] * h0v.z; a0 += w0[3] * h0v.w;
            a1 += w1[0] * h1v.x; a1 += w1[1] * h1v.y; a1 += w1[2] * h1v.z; a1 += w1[3] * h1v.w;
            a2 += w2[0] * h2v.x; a2 += w2[1] * h2v.y; a2 += w2[2] * h2v.z; a2 += w2[3] * h2v.w;
            a3 += w3[0] * h3v.x; a3 += w3[1] * h3v.y; a3 += w3[2] * h3v.z; a3 += w3[3] * h3v.w;
        }
        pacc[d][w][lane] = (a0 + a1) + (a2 + a3);
        __syncthreads();                       // B(t): pacc[d] complete

        if (w == P) {
            // ---- finisher: row = P*64 + lane
            float s = xp_cur;
            #pragma unroll
            for (int g = 0; g < NP; ++g) s += pacc[d][g][lane];
            float hval = fast_tanh(s);
            hcur = hval;                       // own slice for next step (regs!)
            if (t + 1 < Tt) {
                unsigned long long msg =
                    ((unsigned long long)(unsigned)(t + 1) << 32) |
                    (unsigned long long)__float_as_uint(hval);
                __hip_atomic_store(&xb[(size_t)d * Hh + P * RP + lane], msg,
                                   __ATOMIC_RELAXED, __HIP_MEMORY_SCOPE_AGENT);
                ob[(size_t)t * Hh + P * RP + lane] = hval;
                xp_cur = ob[(size_t)(t + 1) * Hh + P * RP + lane];   // prefetch
            } else {
                ob[(size_t)t * Hh + P * RP + lane] = hval;
                out[(size_t)Bb * Tt * Hh + (size_t)c * Hh + P * RP + lane] = hval;
            }
        } else if (t + 1 < Tt) {
            // ---- poll slice w of h_t: R7-proven encoding (relaxed agent)
            const unsigned want = (unsigned)(t + 1);
            unsigned long long msg;
            do {
                msg = __hip_atomic_load(&xb[(size_t)d * Hh + w * RP + lane],
                                        __ATOMIC_RELAXED, __HIP_MEMORY_SCOPE_AGENT);
            } while ((unsigned)(msg >> 32) != want);
            hcur = __uint_as_float((unsigned)msg);
        }
        // no second barrier: pacc is double-buffered, hscratch is wave-private
    }
}

// ---------------- Fallback single-block scan (tiny ws) ----------------
__global__ __launch_bounds__(512)
void rnn_scan_sb(const float* __restrict__ W, const float* __restrict__ h0,
                 float* __restrict__ out)
{
    const int b = blockIdx.x;
    const int j = threadIdx.x;
    __shared__ float hsb[2][Hh];
    hsb[0][j] = h0[(size_t)b * Hh + j];
    __syncthreads();

    float* ob = out + (size_t)b * Tt * Hh;
    const float* wbase = W + (size_t)j * Hh;

    float xp_cur = ob[j];
    int cur = 0;
    for (int t = 0; t < Tt; ++t) {
        float xp_next = (t + 1 < Tt) ? ob[(size_t)(t + 1) * Hh + j] : 0.0f;
        float4 a = make_float4(xp_cur, 0.0f, 0.0f, 0.0f);
        const float* h = hsb[cur];
        #pragma unroll 8
        for (int c4 = 0; c4 < Hh / 4; ++c4) {
            float4 wv = *reinterpret_cast<const float4*>(&wbase[c4 * 4]);
            float4 hv = *reinterpret_cast<const float4*>(&h[c4 * 4]);
            a.x += wv.x * hv.x; a.y += wv.y * hv.y;
            a.z += wv.z * hv.z; a.w += wv.w * hv.w;
        }
        float hn = tanhf((a.x + a.y) + (a.z + a.w));
        hsb[cur ^ 1][j] = hn;
        ob[(size_t)t * Hh + j] = hn;
        xp_cur = xp_next;
        cur ^= 1;
        __syncthreads();
    }
    out[(size_t)Bb * Tt * Hh + (size_t)b * Hh + j] = hsb[cur][j];
}

extern "C" void kernel_launch(void* const* d_in, const int* in_sizes, int n_in,
                              void* d_out, int out_size, void* d_ws, size_t ws_size,
                              hipStream_t stream)
{
    const float* x  = (const float*)d_in[0];
    const float* h0 = (const float*)d_in[1];
    const float* Wx = (const float*)d_in[2];
    const float* bx = (const float*)d_in[3];
    const float* Wh = (const float*)d_in[4];
    const float* bh = (const float*)d_in[5];
    float* out = (float*)d_out;

    dim3 g1(Bb * Tt / 128, Hh / 128);     // (512, 4)
    xproj_gemm<<<g1, 256, 0, stream>>>(x, Wx, bx, bh, out);

    const size_t xb_bytes = (size_t)Bb * 2 * Hh * sizeof(unsigned long long); // 256 KB
    if (ws_size >= xb_bytes) {
        unsigned long long* xbuf = (unsigned long long*)d_ws;
        zero_xbuf<<<64, 512, 0, stream>>>(xbuf);
        void* args[] = {(void*)&Wh, (void*)&h0, (void*)&out, (void*)&xbuf};
        hipLaunchCooperativeKernel((void*)rnn_scan_mb, dim3(NP * Bb), dim3(512),
                                   args, 0, stream);
    } else {
        rnn_scan_sb<<<Bb, Hh, 0, stream>>>(Wh, h0, out);
    }
}